// Round 8
// baseline (643.462 us; speedup 1.0000x reference)
//
#include <hip/hip_runtime.h>
#include <hip/hip_bf16.h>
#include <hip/hip_cooperative_groups.h>
#include <math.h>

namespace cg = cooperative_groups;

#define HID 128

typedef __attribute__((ext_vector_type(8))) short short8;
typedef __attribute__((ext_vector_type(4))) short short4v;
typedef __attribute__((ext_vector_type(4))) float f32x4;
typedef __attribute__((ext_vector_type(4))) int int4v;
typedef __attribute__((ext_vector_type(2))) unsigned int uint2v;
typedef __attribute__((ext_vector_type(4))) unsigned short ushort4v;
typedef __attribute__((ext_vector_type(2))) unsigned short ushort2v;
typedef __attribute__((ext_vector_type(2))) _Float16 half2v;

static inline size_t align256(size_t x){ return (x + 255) & ~(size_t)255; }

__device__ inline float bf2f(unsigned short h) {
  union { unsigned u; float f; } uf; uf.u = ((unsigned)h) << 16; return uf.f;
}
__device__ inline unsigned short f2bf(float f) {
  union { float f; unsigned u; } uf; uf.f = f;
  unsigned r = uf.u + 0x7fff + ((uf.u >> 16) & 1);  // RNE
  return (unsigned short)(r >> 16);
}
__device__ inline unsigned short f2h(float f) {
  union { _Float16 h; unsigned short u; } c; c.h = (_Float16)f; return c.u;
}
__device__ inline half2v b2h2(unsigned u) {
  union { unsigned u; half2v h; } c; c.u = u; return c.h;
}

// sum across each 16-lane group (DPP row) — pure VALU, no LDS pipe
__device__ inline float dpp_rsum16(float x) {
  int v;
  v = __builtin_amdgcn_update_dpp(0, __float_as_int(x), 0xB1, 0xF, 0xF, true);  // quad_perm [1,0,3,2]
  x += __int_as_float(v);
  v = __builtin_amdgcn_update_dpp(0, __float_as_int(x), 0x4E, 0xF, 0xF, true);  // quad_perm [2,3,0,1]
  x += __int_as_float(v);
  v = __builtin_amdgcn_update_dpp(0, __float_as_int(x), 0x124, 0xF, 0xF, true); // row_ror:4
  x += __int_as_float(v);
  v = __builtin_amdgcn_update_dpp(0, __float_as_int(x), 0x128, 0xF, 0xF, true); // row_ror:8
  x += __int_as_float(v);
  return x;
}

// =============== cooperative CSR mega-kernel =================================
// phase0: wprep (blocks 0-127) || zero deg (blocks 128+)
// phase1: hist + rank        phase2: two-step scan        phase3: scatter
__global__ __launch_bounds__(512) void k_csr(
    const float* W0, const float* W1, const float* W2, const float* W3,
    const float* W4, const float* W5, const float* W6, const float* W7,
    const float* b0, const float* b1, const float* b2, const float* b3,
    const float* b4, const float* b5, const float* b6, const float* b7,
    unsigned short* Wcat, float* Bcat,
    const int* __restrict__ esrc, const int* __restrict__ edst,
    int* __restrict__ deg, int* __restrict__ rank,
    int* __restrict__ rowptr, int* __restrict__ bsum, int* __restrict__ csrc,
    int e, int n)
{
  cg::grid_group grid = cg::this_grid();
  __shared__ float tl[32][33];
  __shared__ int tmp[512];
  __shared__ int sred[8];
  __shared__ int base_sh;
  const int t = threadIdx.x, bid = blockIdx.x;

  // ---- phase 0 ----
  if (bid < 128) {
    const float* Ws[8] = {W0, W1, W2, W3, W4, W5, W6, W7};
    const float* bs[8] = {b0, b1, b2, b3, b4, b5, b6, b7};
    int m = bid >> 4, tile = bid & 15;
    int tr = (tile >> 2) * 32, tc = (tile & 3) * 32;
    int tx = t & 31, ty = t >> 5;   // 32 x 16
    const float* Wm = Ws[m];
    #pragma unroll
    for (int r = 0; r < 32; r += 16) tl[ty + r][tx] = Wm[(tr + ty + r) * 128 + tc + tx];
    __syncthreads();
    #pragma unroll
    for (int r = 0; r < 32; r += 16)
      Wcat[m * 16384 + (tc + ty + r) * 128 + tr + tx] = f2bf(tl[tx][ty + r]);
    if (tile == 0 && t < 128) Bcat[m * 128 + t] = bs[m][t];
  } else {
    for (int i = (bid - 128) * 512 + t; i < n; i += 384 * 512) deg[i] = 0;
  }
  grid.sync();

  // ---- phase 1: hist + rank ----
  for (int i = bid * 512 + t; i < e; i += 512 * 512)
    rank[i] = atomicAdd(&deg[edst[i]], 1);
  grid.sync();

  // ---- phase 2a: block-local exclusive scan ----
  const int SB = (n + 511) >> 9;
  if (bid < SB) {
    int i = bid * 512 + t;
    int v = (i < n) ? deg[i] : 0;
    tmp[t] = v;
    __syncthreads();
    for (int off = 1; off < 512; off <<= 1) {
      int u = (t >= off) ? tmp[t - off] : 0;
      __syncthreads();
      tmp[t] += u;
      __syncthreads();
    }
    if (i < n) rowptr[i] = tmp[t] - v;
    if (t == 511) bsum[bid] = tmp[t];
  }
  grid.sync();

  // ---- phase 2b: apply block prefix ----
  if (bid < SB) {
    int v = (t < SB && t < bid) ? bsum[t] : 0;
    #pragma unroll
    for (int off = 32; off >= 1; off >>= 1) v += __shfl_xor(v, off);
    if ((t & 63) == 0) sred[t >> 6] = v;
    __syncthreads();
    if (t == 0) {
      int b = 0;
      #pragma unroll
      for (int j = 0; j < 8; ++j) b += sred[j];
      base_sh = b;
    }
    __syncthreads();
    int i = bid * 512 + t;
    if (i < n) rowptr[i] += base_sh;
    if (i == 0) rowptr[n] = e;
  }
  grid.sync();

  // ---- phase 3: atomic-free scatter ----
  for (int i = bid * 512 + t; i < e; i += 512 * 512)
    csrc[rowptr[edst[i]] + rank[i]] = esrc[i] << 9;   // byte offset into KVb
}

// ---------------- fused QKVS projection GEMM (bf16 MFMA, dbuf W, 4 phases) ----
// outputs: Q (f16, pre-scaled by log2e/sqrt(32)), KV interleaved (f16), S (f16)
template<int ABF16>
__global__ __launch_bounds__(256, 2) void k_qkvs(
    const void* __restrict__ Ain, const unsigned short* __restrict__ Wl,
    const float* __restrict__ Bl, unsigned short* __restrict__ Qb,
    unsigned short* __restrict__ KVb, unsigned short* __restrict__ Sb, int n)
{
  __shared__ unsigned short sA[64 * 128];        // 16 KB
  __shared__ unsigned short sW[2][128 * 128];    // 2 x 32 KB
  const int tid = threadIdx.x;
  const int rb = blockIdx.x * 64;
  const float QSC = 0.25503487f;   // (1/sqrt(32)) * log2(e)

  short8 wreg[8];
  auto loadW = [&](int y) {
    const unsigned short* Wy = Wl + (size_t)y * 16384;
    #pragma unroll
    for (int it = 0; it < 8; ++it) {
      int q = tid + it * 256;
      wreg[it] = *reinterpret_cast<const short8*>(Wy + q * 8);
    }
  };
  auto storeW = [&](unsigned short* buf) {
    #pragma unroll
    for (int it = 0; it < 8; ++it) {
      int q = tid + it * 256;
      int c = q >> 4, ch = q & 15;
      *reinterpret_cast<short8*>(&buf[c * 128 + ((ch ^ (c & 7)) << 3)]) = wreg[it];
    }
  };

  loadW(0);
  storeW(sW[0]);
  if (ABF16) {
    const unsigned short* A = (const unsigned short*)Ain;
    #pragma unroll
    for (int it = 0; it < 4; ++it) {
      int q = tid + it * 256;
      int row = q >> 4, ch = q & 15;
      int gr = rb + row;
      short8 h = {0,0,0,0,0,0,0,0};
      if (gr < n) h = *reinterpret_cast<const short8*>(A + (size_t)gr * HID + ch * 8);
      *reinterpret_cast<short8*>(&sA[row * 128 + ((ch ^ (row & 7)) << 3)]) = h;
    }
  } else {
    const float* A = (const float*)Ain;
    #pragma unroll
    for (int it = 0; it < 8; ++it) {
      int q = tid + it * 256;
      int row = q >> 5, c4 = (q & 31) * 4;
      int gr = rb + row;
      f32x4 a = {0.f, 0.f, 0.f, 0.f};
      if (gr < n) a = *reinterpret_cast<const f32x4*>(A + (size_t)gr * HID + c4);
      short4v h;
      h.x = (short)f2bf(a.x); h.y = (short)f2bf(a.y);
      h.z = (short)f2bf(a.z); h.w = (short)f2bf(a.w);
      int eloff = row * 128 + (((c4 >> 3) ^ (row & 7)) << 3) + (c4 & 7);
      *reinterpret_cast<short4v*>(&sA[eloff]) = h;
    }
  }
  __syncthreads();

  const int lane = tid & 63;
  const int wv = tid >> 6;

  short8 af[4];
  #pragma unroll
  for (int ks = 0; ks < 4; ++ks) {
    int ch = ks * 4 + (lane >> 4);
    int row = wv * 16 + (lane & 15);
    af[ks] = *reinterpret_cast<const short8*>(&sA[row * 128 + ((ch ^ (row & 7)) << 3)]);
  }

  f32x4 acc[8];
  auto compute = [&](const unsigned short* buf) {
    #pragma unroll
    for (int mf = 0; mf < 8; ++mf) acc[mf] = (f32x4){0.f, 0.f, 0.f, 0.f};
    #pragma unroll
    for (int ks = 0; ks < 4; ++ks) {
      int ch = ks * 4 + (lane >> 4);
      short8 wf[8];
      #pragma unroll
      for (int mf = 0; mf < 8; ++mf) {
        int wc = mf * 16 + (lane & 15);
        wf[mf] = *reinterpret_cast<const short8*>(&buf[wc * 128 + ((ch ^ (wc & 7)) << 3)]);
      }
      #pragma unroll
      for (int mf = 0; mf < 8; ++mf)
        acc[mf] = __builtin_amdgcn_mfma_f32_16x16x32_bf16(wf[mf], af[ks], acc[mf], 0, 0, 0);
    }
  };

  const int gr = rb + wv * 16 + (lane & 15);
  const int cbase = (lane >> 4) << 2;

  // ---- phase 0: Q (f16, pre-scaled); stage W[3] under it ----
  loadW(3);
  compute(sW[0]);
  if (gr < n) {
    #pragma unroll
    for (int mf = 0; mf < 8; ++mf) {
      int c0 = mf * 16 + cbase;
      f32x4 b = *reinterpret_cast<const f32x4*>(Bl + 0 * 128 + c0);
      f32x4 v = acc[mf];
      ushort4v h;
      h.x = f2h((v.x + b.x) * QSC); h.y = f2h((v.y + b.y) * QSC);
      h.z = f2h((v.z + b.z) * QSC); h.w = f2h((v.w + b.w) * QSC);
      *reinterpret_cast<ushort4v*>(Qb + (size_t)gr * HID + c0) = h;
    }
  }
  storeW(sW[1]);
  __syncthreads();

  // ---- phase 1: S (f16); stage W[1] under it ----
  loadW(1);
  compute(sW[1]);
  if (gr < n) {
    #pragma unroll
    for (int mf = 0; mf < 8; ++mf) {
      int c0 = mf * 16 + cbase;
      f32x4 b = *reinterpret_cast<const f32x4*>(Bl + 3 * 128 + c0);
      f32x4 v = acc[mf];
      ushort4v h;
      h.x = f2h(v.x + b.x); h.y = f2h(v.y + b.y);
      h.z = f2h(v.z + b.z); h.w = f2h(v.w + b.w);
      *reinterpret_cast<ushort4v*>(Sb + (size_t)gr * HID + c0) = h;
    }
  }
  storeW(sW[0]);
  __syncthreads();

  // ---- phase 2: K (held in registers); stage W[2] under it ----
  loadW(2);
  compute(sW[0]);
  f32x4 kacc[8];
  #pragma unroll
  for (int mf = 0; mf < 8; ++mf) kacc[mf] = acc[mf];
  storeW(sW[1]);
  __syncthreads();

  // ---- phase 3: V, store interleaved KV (f16) ----
  compute(sW[1]);
  if (gr < n) {
    #pragma unroll
    for (int mf = 0; mf < 8; ++mf) {
      int c0 = mf * 16 + cbase;
      f32x4 bk = *reinterpret_cast<const f32x4*>(Bl + 1 * 128 + c0);
      f32x4 bv = *reinterpret_cast<const f32x4*>(Bl + 2 * 128 + c0);
      f32x4 kv = kacc[mf], vv = acc[mf];
      short8 h;
      h[0] = (short)f2h(kv.x + bk.x); h[1] = (short)f2h(kv.y + bk.y);
      h[2] = (short)f2h(vv.x + bv.x); h[3] = (short)f2h(vv.y + bv.y);
      h[4] = (short)f2h(kv.z + bk.z); h[5] = (short)f2h(kv.w + bk.w);
      h[6] = (short)f2h(vv.z + bv.z); h[7] = (short)f2h(vv.w + bv.w);
      *reinterpret_cast<short8*>(KVb + (size_t)gr * 256 + 2 * c0) = h;
    }
  }
}

// ---------------- fused attention + skip + relu (f16, 8-deep pipeline) ----------------
__global__ __launch_bounds__(256, 6) void k_attn2(
    const unsigned short* __restrict__ Qb, const unsigned short* __restrict__ KVb,
    const unsigned short* __restrict__ Sb, const int* __restrict__ rowptr,
    const int* __restrict__ csrc, unsigned short* __restrict__ Hout, int n)
{
  int wid = blockIdx.x * 4 + (threadIdx.x >> 6);
  if (wid >= n) return;
  int lane = threadIdx.x & 63;
  half2v qh = b2h2(*reinterpret_cast<const unsigned*>(Qb + (size_t)wid * HID + 2 * lane));
  int e0 = rowptr[wid], deg = rowptr[wid + 1] - e0;
  const int* cp = csrc + e0;
  const char* kvb = (const char*)KVb + lane * 8;
  float m = -INFINITY, s = 0.f, a0 = 0.f, a1 = 0.f;

  auto LDo = [&](int off) -> uint2v {
    return *reinterpret_cast<const uint2v*>(kvb + (unsigned)off);
  };
  auto proc1 = [&](uint2v kv) {
    float lg = dpp_rsum16(__builtin_amdgcn_fdot2(qh, b2h2(kv.x), 0.f, false));
    if (!__all(lg <= m + 11.5f)) {
      float nm = fmaxf(m, lg);
      float cc = __builtin_amdgcn_exp2f(m - nm);
      s *= cc; a0 *= cc; a1 *= cc; m = nm;
    }
    float p = __builtin_amdgcn_exp2f(lg - m);
    half2v vh = b2h2(kv.y);
    s += p;
    a0 = fmaf(p, (float)vh.x, a0);
    a1 = fmaf(p, (float)vh.y, a1);
  };
  auto proc4 = [&](uint2v e0v, uint2v e1v, uint2v e2v, uint2v e3v) {
    float l0 = dpp_rsum16(__builtin_amdgcn_fdot2(qh, b2h2(e0v.x), 0.f, false));
    float l1 = dpp_rsum16(__builtin_amdgcn_fdot2(qh, b2h2(e1v.x), 0.f, false));
    float l2 = dpp_rsum16(__builtin_amdgcn_fdot2(qh, b2h2(e2v.x), 0.f, false));
    float l3 = dpp_rsum16(__builtin_amdgcn_fdot2(qh, b2h2(e3v.x), 0.f, false));
    float qm = fmaxf(fmaxf(l0, l1), fmaxf(l2, l3));
    if (!__all(qm <= m + 11.5f)) {       // rare, wave-uniform
      float nm = fmaxf(m, qm);
      float cc = __builtin_amdgcn_exp2f(m - nm);
      s *= cc; a0 *= cc; a1 *= cc; m = nm;
    }
    float p0 = __builtin_amdgcn_exp2f(l0 - m);
    float p1 = __builtin_amdgcn_exp2f(l1 - m);
    float p2 = __builtin_amdgcn_exp2f(l2 - m);
    float p3 = __builtin_amdgcn_exp2f(l3 - m);
    s += (p0 + p1) + (p2 + p3);
    half2v v0 = b2h2(e0v.y), v1 = b2h2(e1v.y), v2 = b2h2(e2v.y), v3 = b2h2(e3v.y);
    a0 = fmaf(p3, (float)v3.x, fmaf(p2, (float)v2.x, fmaf(p1, (float)v1.x, fmaf(p0, (float)v0.x, a0))));
    a1 = fmaf(p3, (float)v3.y, fmaf(p2, (float)v2.y, fmaf(p1, (float)v1.y, fmaf(p0, (float)v0.y, a1))));
  };

  int nq = deg >> 2, r = deg & 3;
  if (nq >= 2) {
    int4v o0; __builtin_memcpy(&o0, cp, 16);
    int4v o1; __builtin_memcpy(&o1, cp + 4, 16);
    uint2v A0 = LDo(o0.x), A1 = LDo(o0.y), A2 = LDo(o0.z), A3 = LDo(o0.w);
    uint2v B0 = LDo(o1.x), B1 = LDo(o1.y), B2 = LDo(o1.z), B3 = LDo(o1.w);
    for (int q = 2; q < nq; ++q) {
      int4v no; __builtin_memcpy(&no, cp + 4 * q, 16);
      uint2v N0 = LDo(no.x), N1 = LDo(no.y), N2 = LDo(no.z), N3 = LDo(no.w);
      proc4(A0, A1, A2, A3);
      A0 = B0; A1 = B1; A2 = B2; A3 = B3;
      B0 = N0; B1 = N1; B2 = N2; B3 = N3;
    }
    proc4(A0, A1, A2, A3);
    proc4(B0, B1, B2, B3);
  } else if (nq == 1) {
    int4v o; __builtin_memcpy(&o, cp, 16);
    proc4(LDo(o.x), LDo(o.y), LDo(o.z), LDo(o.w));
  }
  int tb = nq * 4;
  for (int i = 0; i < r; ++i) proc1(LDo(cp[tb + i]));

  float inv = (s > 0.f) ? 1.f / s : 0.f;
  half2v sh = b2h2(*reinterpret_cast<const unsigned*>(Sb + (size_t)wid * HID + 2 * lane));
  ushort2v h;
  h.x = f2bf(fmaxf(fmaf(a0, inv, (float)sh.x), 0.f));
  h.y = f2bf(fmaxf(fmaf(a1, inv, (float)sh.y), 0.f));
  *reinterpret_cast<ushort2v*>(Hout + (size_t)wid * HID + 2 * lane) = h;
}

// ---------------- fused mean-pool + FC (64 blocks; coalesced uint row reads) ----------
__global__ __launch_bounds__(256) void k_poolfc(
    const unsigned short* __restrict__ H, const int* __restrict__ batch,
    const float* __restrict__ Wfc, const float* __restrict__ bfc,
    float* __restrict__ out, int n)
{
  int g = blockIdx.x;
  int lo = 0, hi = n;
  while (lo < hi) { int mid = (lo + hi) >> 1; if (batch[mid] < g) lo = mid + 1; else hi = mid; }
  int start = lo;
  hi = n;
  while (lo < hi) { int mid = (lo + hi) >> 1; if (batch[mid] < g + 1) lo = mid + 1; else hi = mid; }
  int end = lo;

  int t = threadIdx.x, w = t >> 6, l = t & 63;
  const unsigned* Hu = (const unsigned*)H;    // one row = 64 uints (2 bf16 each)
  float a0 = 0.f, a1 = 0.f;
  for (int i = start + w; i < end; i += 4) {
    unsigned u = Hu[(size_t)i * 64 + l];
    a0 += bf2f((unsigned short)(u & 0xffff));
    a1 += bf2f((unsigned short)(u >> 16));
  }
  __shared__ float part[4][64][2];
  part[w][l][0] = a0; part[w][l][1] = a1;
  __syncthreads();
  if (w == 0) {
    float s0 = part[0][l][0] + part[1][l][0] + part[2][l][0] + part[3][l][0];
    float s1 = part[0][l][1] + part[1][l][1] + part[2][l][1] + part[3][l][1];
    float v = s0 * Wfc[2 * l] + s1 * Wfc[2 * l + 1];
    #pragma unroll
    for (int off = 32; off >= 1; off >>= 1) v += __shfl_xor(v, off);
    if (l == 0) out[g] = v / fmaxf((float)(end - start), 1.f) + bfc[0];
  }
}

extern "C" void kernel_launch(void* const* d_in, const int* in_sizes, int n_in,
                              void* d_out, int out_size, void* d_ws, size_t ws_size,
                              hipStream_t stream)
{
  const float* x   = (const float*)d_in[0];
  const int*   ei  = (const int*)d_in[1];
  const int*   bat = (const int*)d_in[2];
  const float *Wq1 = (const float*)d_in[3],  *bq1 = (const float*)d_in[4];
  const float *Wk1 = (const float*)d_in[5],  *bk1 = (const float*)d_in[6];
  const float *Wv1 = (const float*)d_in[7],  *bv1 = (const float*)d_in[8];
  const float *Ws1 = (const float*)d_in[9],  *bs1 = (const float*)d_in[10];
  const float *Wq2 = (const float*)d_in[11], *bq2 = (const float*)d_in[12];
  const float *Wk2 = (const float*)d_in[13], *bk2 = (const float*)d_in[14];
  const float *Wv2 = (const float*)d_in[15], *bv2 = (const float*)d_in[16];
  const float *Ws2 = (const float*)d_in[17], *bs2 = (const float*)d_in[18];
  const float *Wfc = (const float*)d_in[19], *bfc = (const float*)d_in[20];
  float* out = (float*)d_out;

  const int N = in_sizes[0] / HID;
  const int E = in_sizes[1] / 2;
  const int G = 64;

  char* p = (char*)d_ws;
  auto alloc = [&](size_t bytes) -> char* { char* r = p; p += align256(bytes); return r; };
  unsigned short* Qb  = (unsigned short*)alloc((size_t)N * HID * 2);   // f16
  unsigned short* KVb = (unsigned short*)alloc((size_t)N * 256 * 2);   // f16 interleaved
  unsigned short* Sb  = (unsigned short*)alloc((size_t)N * HID * 2);   // f16
  unsigned short* Hb  = (unsigned short*)alloc((size_t)N * HID * 2);   // bf16
  unsigned short* H2b = (unsigned short*)alloc((size_t)N * HID * 2);   // bf16
  unsigned short* Wcat = (unsigned short*)alloc((size_t)8 * 128 * 128 * 2);
  float* Bcat = (float*)alloc((size_t)8 * 128 * 4);
  int* rowptr = (int*)alloc((size_t)(N + 1) * sizeof(int));
  int* deg    = (int*)alloc((size_t)N * sizeof(int));
  int* rank   = (int*)alloc((size_t)E * sizeof(int));
  int* bsum   = (int*)alloc(4096);
  int* csrc   = (int*)alloc((size_t)E * sizeof(int));

  const int* esrc = ei;
  const int* edst = ei + E;

  // one cooperative kernel: wprep || zero-deg, hist+rank, scan, scatter
  void* cargs[] = {
    (void*)&Wq1, (void*)&Wk1, (void*)&Wv1, (void*)&Ws1,
    (void*)&Wq2, (void*)&Wk2, (void*)&Wv2, (void*)&Ws2,
    (void*)&bq1, (void*)&bk1, (void*)&bv1, (void*)&bs1,
    (void*)&bq2, (void*)&bk2, (void*)&bv2, (void*)&bs2,
    (void*)&Wcat, (void*)&Bcat,
    (void*)&esrc, (void*)&edst,
    (void*)&deg, (void*)&rank, (void*)&rowptr, (void*)&bsum, (void*)&csrc,
    (void*)&E, (void*)&N
  };
  hipLaunchCooperativeKernel((const void*)k_csr, dim3(512), dim3(512), cargs, 0, stream);

  int QB = (N + 63) / 64;
  // layer 1 (fp32 input)
  k_qkvs<0><<<QB, 256, 0, stream>>>(x, Wcat, Bcat, Qb, KVb, Sb, N);
  k_attn2<<<(N + 3) / 4, 256, 0, stream>>>(Qb, KVb, Sb, rowptr, csrc, Hb, N);
  // layer 2 (bf16 input)
  k_qkvs<1><<<QB, 256, 0, stream>>>(Hb, Wcat + 4 * 16384, Bcat + 512, Qb, KVb, Sb, N);
  k_attn2<<<(N + 3) / 4, 256, 0, stream>>>(Qb, KVb, Sb, rowptr, csrc, H2b, N);
  // mean-pool + fc
  k_poolfc<<<G, 256, 0, stream>>>(H2b, bat, Wfc, bfc, out, N);
}

// Round 10
// 364.719 us; speedup vs baseline: 1.7643x; 1.7643x over previous
//
#include <hip/hip_runtime.h>
#include <hip/hip_bf16.h>
#include <math.h>

#define HID 128

typedef __attribute__((ext_vector_type(8))) short short8;
typedef __attribute__((ext_vector_type(4))) short short4v;
typedef __attribute__((ext_vector_type(4))) float f32x4;
typedef __attribute__((ext_vector_type(4))) int int4v;
typedef __attribute__((ext_vector_type(4))) unsigned int uint4v;
typedef __attribute__((ext_vector_type(4))) unsigned short ushort4v;
typedef __attribute__((ext_vector_type(2))) unsigned short ushort2v;
typedef __attribute__((ext_vector_type(2))) _Float16 half2v;

static inline size_t align256(size_t x){ return (x + 255) & ~(size_t)255; }

__device__ inline float bf2f(unsigned short h) {
  union { unsigned u; float f; } uf; uf.u = ((unsigned)h) << 16; return uf.f;
}
__device__ inline unsigned short f2bf(float f) {
  union { float f; unsigned u; } uf; uf.f = f;
  unsigned r = uf.u + 0x7fff + ((uf.u >> 16) & 1);  // RNE
  return (unsigned short)(r >> 16);
}
__device__ inline unsigned short f2h(float f) {
  union { _Float16 h; unsigned short u; } c; c.h = (_Float16)f; return c.u;
}
__device__ inline half2v b2h2(unsigned u) {
  union { unsigned u; half2v h; } c; c.u = u; return c.h;
}

// sum across each 8-lane group — pure VALU DPP (xor1, xor2, half-mirror)
__device__ inline float dpp_rsum8(float x) {
  int v;
  v = __builtin_amdgcn_update_dpp(0, __float_as_int(x), 0xB1, 0xF, 0xF, true);   // quad_perm [1,0,3,2]
  x += __int_as_float(v);
  v = __builtin_amdgcn_update_dpp(0, __float_as_int(x), 0x4E, 0xF, 0xF, true);   // quad_perm [2,3,0,1]
  x += __int_as_float(v);
  v = __builtin_amdgcn_update_dpp(0, __float_as_int(x), 0x141, 0xF, 0xF, true);  // row_half_mirror
  x += __int_as_float(v);
  return x;
}

// ---- fused: weight prep (blocks 0-127) || hist+rank (blocks 128+) ----
__global__ __launch_bounds__(512) void k_prep(
    const float* W0, const float* W1, const float* W2, const float* W3,
    const float* W4, const float* W5, const float* W6, const float* W7,
    const float* b0, const float* b1, const float* b2, const float* b3,
    const float* b4, const float* b5, const float* b6, const float* b7,
    unsigned short* Wcat, float* Bcat,
    const int* __restrict__ edst, int* __restrict__ deg, int* __restrict__ rank, int e)
{
  __shared__ float tl[32][33];
  int t = threadIdx.x;
  if (blockIdx.x >= 128) {
    for (int i = (blockIdx.x - 128) * 512 + t; i < e; i += 512 * 512)
      rank[i] = atomicAdd(&deg[edst[i]], 1);
    return;
  }
  const float* Ws[8] = {W0, W1, W2, W3, W4, W5, W6, W7};
  const float* bs[8] = {b0, b1, b2, b3, b4, b5, b6, b7};
  int m = blockIdx.x >> 4, tile = blockIdx.x & 15;
  int tr = (tile >> 2) * 32, tc = (tile & 3) * 32;
  int tx = t & 31, ty = t >> 5;   // 32 x 16
  const float* Wm = Ws[m];
  #pragma unroll
  for (int r = 0; r < 32; r += 16) tl[ty + r][tx] = Wm[(tr + ty + r) * 128 + tc + tx];
  __syncthreads();
  #pragma unroll
  for (int r = 0; r < 32; r += 16)
    Wcat[m * 16384 + (tc + ty + r) * 128 + tr + tx] = f2bf(tl[tx][ty + r]);
  if (tile == 0 && t < 128) Bcat[m * 128 + t] = bs[m][t];
}

// ---------------- CSR scan ----------------
__global__ void k_scan_a(const int* __restrict__ deg, int* __restrict__ rowptr,
                         int* __restrict__ bsum, int n) {
  __shared__ int tmp[512];
  int t = threadIdx.x, i = blockIdx.x * 512 + t;
  int v = (i < n) ? deg[i] : 0;
  tmp[t] = v;
  __syncthreads();
  for (int off = 1; off < 512; off <<= 1) {
    int u = (t >= off) ? tmp[t - off] : 0;
    __syncthreads();
    tmp[t] += u;
    __syncthreads();
  }
  if (i < n) rowptr[i] = tmp[t] - v;
  if (t == 511) bsum[blockIdx.x] = tmp[t];
}

__global__ void k_scan_c(int* __restrict__ rowptr, const int* __restrict__ bsum,
                         int n, int e, int nb) {
  __shared__ int sred[8];
  __shared__ int base_sh;
  int t = threadIdx.x;
  int v = (t < nb && t < (int)blockIdx.x) ? bsum[t] : 0;
  #pragma unroll
  for (int off = 32; off >= 1; off >>= 1) v += __shfl_xor(v, off);
  if ((t & 63) == 0) sred[t >> 6] = v;
  __syncthreads();
  if (t == 0) {
    int b = 0;
    #pragma unroll
    for (int j = 0; j < 8; ++j) b += sred[j];
    base_sh = b;
  }
  __syncthreads();
  int i = blockIdx.x * 512 + t;
  if (i < n) rowptr[i] += base_sh;
  if (i == 0) rowptr[n] = e;
}

// ---- atomic-free scatter: position = rowptr[dst] + rank (from hist pass) ----
__global__ __launch_bounds__(256) void k_scatter(
    const int* __restrict__ esrc, const int* __restrict__ edst,
    const int* __restrict__ rowptr, const int* __restrict__ rank,
    int* __restrict__ csrc, int e)
{
  for (int i = blockIdx.x * 256 + threadIdx.x; i < e; i += gridDim.x * 256)
    csrc[rowptr[edst[i]] + rank[i]] = esrc[i] << 9;   // byte offset into KVb
}

// ---------------- fused QKVS projection GEMM (bf16 MFMA, 64-row tile, 4 phases) --------
// outputs: Q (f16, pre-scaled), KV quad-interleaved (f16): [k4p..k4p+3, v4p..v4p+3], S (f16)
template<int ABF16>
__global__ __launch_bounds__(256, 3) void k_qkvs(
    const void* __restrict__ Ain, const unsigned short* __restrict__ Wl,
    const float* __restrict__ Bl, unsigned short* __restrict__ Qb,
    unsigned short* __restrict__ KVb, unsigned short* __restrict__ Sb, int n)
{
  __shared__ unsigned short sA[64 * 128];    // 16 KB
  __shared__ unsigned short sW[128 * 128];   // 32 KB
  const int tid = threadIdx.x;
  const int rb = blockIdx.x * 64;
  const float QSC = 0.25503487f;   // (1/sqrt(32)) * log2(e)

  if (ABF16) {
    const unsigned short* A = (const unsigned short*)Ain;
    #pragma unroll
    for (int it = 0; it < 4; ++it) {
      int q = tid + it * 256;
      int row = q >> 4, ch = q & 15;
      int gr = rb + row;
      short8 h = {0,0,0,0,0,0,0,0};
      if (gr < n) h = *reinterpret_cast<const short8*>(A + (size_t)gr * HID + ch * 8);
      *reinterpret_cast<short8*>(&sA[row * 128 + ((ch ^ (row & 7)) << 3)]) = h;
    }
  } else {
    const float* A = (const float*)Ain;
    #pragma unroll
    for (int it = 0; it < 8; ++it) {
      int q = tid + it * 256;
      int row = q >> 5, c4 = (q & 31) * 4;
      int gr = rb + row;
      f32x4 a = {0.f, 0.f, 0.f, 0.f};
      if (gr < n) a = *reinterpret_cast<const f32x4*>(A + (size_t)gr * HID + c4);
      short4v h;
      h.x = (short)f2bf(a.x); h.y = (short)f2bf(a.y);
      h.z = (short)f2bf(a.z); h.w = (short)f2bf(a.w);
      int eloff = row * 128 + (((c4 >> 3) ^ (row & 7)) << 3) + (c4 & 7);
      *reinterpret_cast<short4v*>(&sA[eloff]) = h;
    }
  }

  const int lane = tid & 63;
  const int wv = tid >> 6;

  auto stageW = [&](int y) {
    const unsigned short* Wy = Wl + (size_t)y * 16384;
    #pragma unroll
    for (int it = 0; it < 8; ++it) {
      int q = tid + it * 256;
      int c = q >> 4, ch = q & 15;
      short8 w = *reinterpret_cast<const short8*>(Wy + c * 128 + ch * 8);
      *reinterpret_cast<short8*>(&sW[c * 128 + ((ch ^ (c & 7)) << 3)]) = w;
    }
  };

  stageW(0);
  __syncthreads();

  short8 af[4];
  #pragma unroll
  for (int ks = 0; ks < 4; ++ks) {
    int ch = ks * 4 + (lane >> 4);
    int row = wv * 16 + (lane & 15);
    af[ks] = *reinterpret_cast<const short8*>(&sA[row * 128 + ((ch ^ (row & 7)) << 3)]);
  }

  f32x4 acc[8];
  auto compute = [&]() {
    #pragma unroll
    for (int mf = 0; mf < 8; ++mf) acc[mf] = (f32x4){0.f, 0.f, 0.f, 0.f};
    #pragma unroll
    for (int ks = 0; ks < 4; ++ks) {
      int ch = ks * 4 + (lane >> 4);
      short8 wf[8];
      #pragma unroll
      for (int mf = 0; mf < 8; ++mf) {
        int wc = mf * 16 + (lane & 15);
        wf[mf] = *reinterpret_cast<const short8*>(&sW[wc * 128 + ((ch ^ (wc & 7)) << 3)]);
      }
      #pragma unroll
      for (int mf = 0; mf < 8; ++mf)
        acc[mf] = __builtin_amdgcn_mfma_f32_16x16x32_bf16(wf[mf], af[ks], acc[mf], 0, 0, 0);
    }
  };

  const int gr = rb + wv * 16 + (lane & 15);
  const int cbase = (lane >> 4) << 2;

  // ---- phase 0: Q (f16, pre-scaled) ----
  compute();
  if (gr < n) {
    #pragma unroll
    for (int mf = 0; mf < 8; ++mf) {
      int c0 = mf * 16 + cbase;
      f32x4 b = *reinterpret_cast<const f32x4*>(Bl + 0 * 128 + c0);
      f32x4 v = acc[mf];
      ushort4v h;
      h.x = f2h((v.x + b.x) * QSC); h.y = f2h((v.y + b.y) * QSC);
      h.z = f2h((v.z + b.z) * QSC); h.w = f2h((v.w + b.w) * QSC);
      *reinterpret_cast<ushort4v*>(Qb + (size_t)gr * HID + c0) = h;
    }
  }

  // ---- phase 1: S (f16) ----
  __syncthreads();
  stageW(3);
  __syncthreads();
  compute();
  if (gr < n) {
    #pragma unroll
    for (int mf = 0; mf < 8; ++mf) {
      int c0 = mf * 16 + cbase;
      f32x4 b = *reinterpret_cast<const f32x4*>(Bl + 3 * 128 + c0);
      f32x4 v = acc[mf];
      ushort4v h;
      h.x = f2h(v.x + b.x); h.y = f2h(v.y + b.y);
      h.z = f2h(v.z + b.z); h.w = f2h(v.w + b.w);
      *reinterpret_cast<ushort4v*>(Sb + (size_t)gr * HID + c0) = h;
    }
  }

  // ---- phase 2: K (held in registers) ----
  __syncthreads();
  stageW(1);
  __syncthreads();
  compute();
  f32x4 kacc[8];
  #pragma unroll
  for (int mf = 0; mf < 8; ++mf) kacc[mf] = acc[mf];

  // ---- phase 3: V, store quad-interleaved KV (f16): [k quad | v quad] ----
  __syncthreads();
  stageW(2);
  __syncthreads();
  compute();
  if (gr < n) {
    #pragma unroll
    for (int mf = 0; mf < 8; ++mf) {
      int c0 = mf * 16 + cbase;
      f32x4 bk = *reinterpret_cast<const f32x4*>(Bl + 1 * 128 + c0);
      f32x4 bv = *reinterpret_cast<const f32x4*>(Bl + 2 * 128 + c0);
      f32x4 kv = kacc[mf], vv = acc[mf];
      short8 h;
      h[0] = (short)f2h(kv.x + bk.x); h[1] = (short)f2h(kv.y + bk.y);
      h[2] = (short)f2h(kv.z + bk.z); h[3] = (short)f2h(kv.w + bk.w);
      h[4] = (short)f2h(vv.x + bv.x); h[5] = (short)f2h(vv.y + bv.y);
      h[6] = (short)f2h(vv.z + bv.z); h[7] = (short)f2h(vv.w + bv.w);
      *reinterpret_cast<short8*>(KVb + (size_t)gr * 256 + 2 * c0) = h;
    }
  }
}

// ---------------- fused attention + skip + relu ----------------
// Half-wave edge parallelism: lanes 0-31 process edge 2s, lanes 32-63 edge 2s+1.
// Lane owns 4 features (4l..4l+3) -> one 16B KV load/lane/edge; 8-lane head groups.
// Two online-softmax states merged at the end.
__global__ __launch_bounds__(256, 6) void k_attn2(
    const unsigned short* __restrict__ Qb, const unsigned short* __restrict__ KVb,
    const unsigned short* __restrict__ Sb, const int* __restrict__ rowptr,
    const int* __restrict__ csrc, unsigned short* __restrict__ Hout, int n)
{
  int wid = blockIdx.x * 4 + (threadIdx.x >> 6);
  if (wid >= n) return;
  const int lane = threadIdx.x & 63;
  const int l32 = lane & 31;        // feature-quad index
  const int half = lane >> 5;       // which edge of the pair

  // q features 4*l32 .. 4*l32+3 (already scaled by log2e/sqrt(32))
  uint2 qu = *reinterpret_cast<const uint2*>(Qb + (size_t)wid * HID + 4 * l32);
  half2v qh0 = b2h2(qu.x), qh1 = b2h2(qu.y);

  int e0 = rowptr[wid], deg = rowptr[wid + 1] - e0;
  const int* cp = csrc + e0;
  const char* kvb = (const char*)KVb + l32 * 16;

  float m = -INFINITY, s = 0.f;
  float a0 = 0.f, a1 = 0.f, a2 = 0.f, a3 = 0.f;

  auto LDo = [&](int off) -> uint4v {
    return *reinterpret_cast<const uint4v*>(kvb + (unsigned)off);
  };
  auto logit = [&](uint4v kv) -> float {
    float d = __builtin_amdgcn_fdot2(qh1, b2h2(kv.y),
              __builtin_amdgcn_fdot2(qh0, b2h2(kv.x), 0.f, false), false);
    return dpp_rsum8(d);
  };
  auto accum = [&](float p, uint4v kv) {
    half2v v0 = b2h2(kv.z), v1 = b2h2(kv.w);
    a0 = fmaf(p, (float)v0.x, a0);
    a1 = fmaf(p, (float)v0.y, a1);
    a2 = fmaf(p, (float)v1.x, a2);
    a3 = fmaf(p, (float)v1.y, a3);
  };
  // one batch = 2 steps = 4 edges (2 per half)
  auto procB = [&](uint4v kvA, uint4v kvB) {
    float lA = logit(kvA), lB = logit(kvB);
    float qm = fmaxf(lA, lB);
    if (!__all(qm <= m + 11.5f)) {       // rare, wave-uniform
      float nm = fmaxf(m, qm);
      float cc = __builtin_amdgcn_exp2f(m - nm);
      s *= cc; a0 *= cc; a1 *= cc; a2 *= cc; a3 *= cc; m = nm;
    }
    float pA = __builtin_amdgcn_exp2f(lA - m);
    float pB = __builtin_amdgcn_exp2f(lB - m);
    s += pA + pB;
    accum(pA, kvA);
    accum(pB, kvB);
  };
  // masked single step (tail): edges idx0+half
  auto proc1 = [&](int idx0) {
    int idx = idx0 + half;
    bool valid = idx < deg;
    uint4v kv = LDo(valid ? cp[idx] : 0);
    float lg = logit(kv);
    lg = valid ? lg : -INFINITY;
    if (!__all(lg <= m + 11.5f)) {
      float nm = fmaxf(m, lg);
      float cc = __builtin_amdgcn_exp2f(m - nm);
      s *= cc; a0 *= cc; a1 *= cc; a2 *= cc; a3 *= cc; m = nm;
    }
    float p = valid ? __builtin_amdgcn_exp2f(lg - m) : 0.f;
    s += p;
    accum(p, kv);
  };

  int nb = deg >> 2;           // full 4-edge batches
  if (nb >= 2) {
    int oA0 = cp[0 + half], oA1 = cp[2 + half];
    int oB0 = cp[4 + half], oB1 = cp[6 + half];
    uint4v A0 = LDo(oA0), A1 = LDo(oA1);
    uint4v B0 = LDo(oB0), B1 = LDo(oB1);
    for (int b = 2; b < nb; ++b) {
      int base = 4 * b;
      int n0 = cp[base + half], n1 = cp[base + 2 + half];
      uint4v N0 = LDo(n0), N1 = LDo(n1);
      procB(A0, A1);
      A0 = B0; A1 = B1;
      B0 = N0; B1 = N1;
    }
    procB(A0, A1);
    procB(B0, B1);
  } else if (nb == 1) {
    procB(LDo(cp[half]), LDo(cp[2 + half]));
  }
  int tb = nb * 4, rem = deg - tb;
  if (rem > 0) proc1(tb);
  if (rem > 2) proc1(tb + 2);

  // merge the two half-wave softmax states
  float mo = __shfl_xor(m, 32);
  float so = __shfl_xor(s, 32);
  float b0 = __shfl_xor(a0, 32), b1 = __shfl_xor(a1, 32);
  float b2 = __shfl_xor(a2, 32), b3 = __shfl_xor(a3, 32);
  float M = fmaxf(m, mo);
  float c0 = (m  > -INFINITY) ? __builtin_amdgcn_exp2f(m  - M) : 0.f;
  float c1 = (mo > -INFINITY) ? __builtin_amdgcn_exp2f(mo - M) : 0.f;
  float st = s * c0 + so * c1;
  float inv = (st > 0.f) ? 1.f / st : 0.f;
  float r0 = (a0 * c0 + b0 * c1) * inv;
  float r1 = (a1 * c0 + b1 * c1) * inv;
  float r2 = (a2 * c0 + b2 * c1) * inv;
  float r3 = (a3 * c0 + b3 * c1) * inv;

  if (half == 0) {
    ushort4v sh = *reinterpret_cast<const ushort4v*>(Sb + (size_t)wid * HID + 4 * l32);
    half2v s0 = b2h2((unsigned)sh.x | ((unsigned)sh.y << 16));
    half2v s1 = b2h2((unsigned)sh.z | ((unsigned)sh.w << 16));
    ushort4v h;
    h.x = f2bf(fmaxf(r0 + (float)s0.x, 0.f));
    h.y = f2bf(fmaxf(r1 + (float)s0.y, 0.f));
    h.z = f2bf(fmaxf(r2 + (float)s1.x, 0.f));
    h.w = f2bf(fmaxf(r3 + (float)s1.y, 0.f));
    *reinterpret_cast<ushort4v*>(Hout + (size_t)wid * HID + 4 * l32) = h;
  }
}

// ---------------- fused mean-pool + FC (64 blocks, one per group; zero atomics) --------
__global__ __launch_bounds__(256) void k_poolfc(
    const unsigned short* __restrict__ H, const int* __restrict__ batch,
    const float* __restrict__ Wfc, const float* __restrict__ bfc,
    float* __restrict__ out, int n)
{
  int g = blockIdx.x;
  int lo = 0, hi = n;
  while (lo < hi) { int mid = (lo + hi) >> 1; if (batch[mid] < g) lo = mid + 1; else hi = mid; }
  int start = lo;
  hi = n;
  while (lo < hi) { int mid = (lo + hi) >> 1; if (batch[mid] < g + 1) lo = mid + 1; else hi = mid; }
  int end = lo;

  int t = threadIdx.x;
  int col = t & 127, rr = t >> 7;        // 2 row-streams x 128 cols
  float a0 = 0.f, a1 = 0.f, a2 = 0.f, a3 = 0.f;
  int i = start + rr;
  for (; i + 6 < end; i += 8) {
    a0 += bf2f(H[(size_t)i * HID + col]);
    a1 += bf2f(H[(size_t)(i + 2) * HID + col]);
    a2 += bf2f(H[(size_t)(i + 4) * HID + col]);
    a3 += bf2f(H[(size_t)(i + 6) * HID + col]);
  }
  for (; i < end; i += 2) a0 += bf2f(H[(size_t)i * HID + col]);
  float v = ((a0 + a1) + (a2 + a3)) * Wfc[col];

  __shared__ float red[4];
  #pragma unroll
  for (int off = 32; off >= 1; off >>= 1) v += __shfl_xor(v, off);
  if ((t & 63) == 0) red[t >> 6] = v;
  __syncthreads();
  if (t == 0) {
    float tot = (red[0] + red[1]) + (red[2] + red[3]);
    float cnt = (float)(end - start);
    out[g] = tot / fmaxf(cnt, 1.f) + bfc[0];
  }
}

extern "C" void kernel_launch(void* const* d_in, const int* in_sizes, int n_in,
                              void* d_out, int out_size, void* d_ws, size_t ws_size,
                              hipStream_t stream)
{
  const float* x   = (const float*)d_in[0];
  const int*   ei  = (const int*)d_in[1];
  const int*   bat = (const int*)d_in[2];
  const float *Wq1 = (const float*)d_in[3],  *bq1 = (const float*)d_in[4];
  const float *Wk1 = (const float*)d_in[5],  *bk1 = (const float*)d_in[6];
  const float *Wv1 = (const float*)d_in[7],  *bv1 = (const float*)d_in[8];
  const float *Ws1 = (const float*)d_in[9],  *bs1 = (const float*)d_in[10];
  const float *Wq2 = (const float*)d_in[11], *bq2 = (const float*)d_in[12];
  const float *Wk2 = (const float*)d_in[13], *bk2 = (const float*)d_in[14];
  const float *Wv2 = (const float*)d_in[15], *bv2 = (const float*)d_in[16];
  const float *Ws2 = (const float*)d_in[17], *bs2 = (const float*)d_in[18];
  const float *Wfc = (const float*)d_in[19], *bfc = (const float*)d_in[20];
  float* out = (float*)d_out;

  const int N = in_sizes[0] / HID;
  const int E = in_sizes[1] / 2;
  const int G = 64;

  char* p = (char*)d_ws;
  auto alloc = [&](size_t bytes) -> char* { char* r = p; p += align256(bytes); return r; };
  unsigned short* Qb  = (unsigned short*)alloc((size_t)N * HID * 2);   // f16
  unsigned short* KVb = (unsigned short*)alloc((size_t)N * 256 * 2);   // f16 quad-interleaved
  unsigned short* Sb  = (unsigned short*)alloc((size_t)N * HID * 2);   // f16
  unsigned short* Hb  = (unsigned short*)alloc((size_t)N * HID * 2);   // bf16
  unsigned short* H2b = (unsigned short*)alloc((size_t)N * HID * 2);   // bf16
  unsigned short* Wcat = (unsigned short*)alloc((size_t)8 * 128 * 128 * 2);
  float* Bcat = (float*)alloc((size_t)8 * 128 * 4);
  int* rowptr = (int*)alloc((size_t)(N + 1) * sizeof(int));
  int* deg    = (int*)alloc((size_t)N * sizeof(int));
  int* rank   = (int*)alloc((size_t)E * sizeof(int));
  int* bsum   = (int*)alloc(4096);
  int* csrc   = (int*)alloc((size_t)E * sizeof(int));

  const int* esrc = ei;
  const int* edst = ei + E;

  hipMemsetAsync(deg, 0, (size_t)N * sizeof(int), stream);

  // wprep (blocks 0-127) || hist+rank (blocks 128-639)
  k_prep<<<640, 512, 0, stream>>>(
      Wq1, Wk1, Wv1, Ws1, Wq2, Wk2, Wv2, Ws2,
      bq1, bk1, bv1, bs1, bq2, bk2, bv2, bs2,
      Wcat, Bcat, edst, deg, rank, E);

  int SB = (N + 511) / 512;
  k_scan_a<<<SB, 512, 0, stream>>>(deg, rowptr, bsum, N);
  k_scan_c<<<SB, 512, 0, stream>>>(rowptr, bsum, N, E, SB);
  k_scatter<<<512, 256, 0, stream>>>(esrc, edst, rowptr, rank, csrc, E);

  int QB = (N + 63) / 64;
  // layer 1 (fp32 input)
  k_qkvs<0><<<QB, 256, 0, stream>>>(x, Wcat, Bcat, Qb, KVb, Sb, N);
  k_attn2<<<(N + 3) / 4, 256, 0, stream>>>(Qb, KVb, Sb, rowptr, csrc, Hb, N);
  // layer 2 (bf16 input)
  k_qkvs<1><<<QB, 256, 0, stream>>>(Hb, Wcat + 4 * 16384, Bcat + 512, Qb, KVb, Sb, N);
  k_attn2<<<(N + 3) / 4, 256, 0, stream>>>(Qb, KVb, Sb, rowptr, csrc, H2b, N);
  // mean-pool + fc
  k_poolfc<<<G, 256, 0, stream>>>(H2b, bat, Wfc, bfc, out, N);
}

// Round 11
// 364.392 us; speedup vs baseline: 1.7658x; 1.0009x over previous
//
#include <hip/hip_runtime.h>
#include <hip/hip_bf16.h>
#include <math.h>

#define HID 128

typedef __attribute__((ext_vector_type(8))) short short8;
typedef __attribute__((ext_vector_type(4))) short short4v;
typedef __attribute__((ext_vector_type(4))) float f32x4;
typedef __attribute__((ext_vector_type(4))) unsigned int uint4v;
typedef __attribute__((ext_vector_type(4))) unsigned short ushort4v;
typedef __attribute__((ext_vector_type(2))) _Float16 half2v;

static inline size_t align256(size_t x){ return (x + 255) & ~(size_t)255; }

__device__ inline float bf2f(unsigned short h) {
  union { unsigned u; float f; } uf; uf.u = ((unsigned)h) << 16; return uf.f;
}
__device__ inline unsigned short f2bf(float f) {
  union { float f; unsigned u; } uf; uf.f = f;
  unsigned r = uf.u + 0x7fff + ((uf.u >> 16) & 1);  // RNE
  return (unsigned short)(r >> 16);
}
__device__ inline unsigned short f2h(float f) {
  union { _Float16 h; unsigned short u; } c; c.h = (_Float16)f; return c.u;
}
__device__ inline half2v b2h2(unsigned u) {
  union { unsigned u; half2v h; } c; c.u = u; return c.h;
}

// sum across each 4-lane group — 2 DPP ops
__device__ inline float dpp_rsum4(float x) {
  int v;
  v = __builtin_amdgcn_update_dpp(0, __float_as_int(x), 0xB1, 0xF, 0xF, true);   // quad_perm [1,0,3,2]
  x += __int_as_float(v);
  v = __builtin_amdgcn_update_dpp(0, __float_as_int(x), 0x4E, 0xF, 0xF, true);   // quad_perm [2,3,0,1]
  x += __int_as_float(v);
  return x;
}

// ---- fused: weight prep (blocks 0-127) || hist+rank (blocks 128+) ----
__global__ __launch_bounds__(512) void k_prep(
    const float* W0, const float* W1, const float* W2, const float* W3,
    const float* W4, const float* W5, const float* W6, const float* W7,
    const float* b0, const float* b1, const float* b2, const float* b3,
    const float* b4, const float* b5, const float* b6, const float* b7,
    unsigned short* Wcat, float* Bcat,
    const int* __restrict__ edst, int* __restrict__ deg, int* __restrict__ rank, int e)
{
  __shared__ float tl[32][33];
  int t = threadIdx.x;
  if (blockIdx.x >= 128) {
    for (int i = (blockIdx.x - 128) * 512 + t; i < e; i += 512 * 512)
      rank[i] = atomicAdd(&deg[edst[i]], 1);
    return;
  }
  const float* Ws[8] = {W0, W1, W2, W3, W4, W5, W6, W7};
  const float* bs[8] = {b0, b1, b2, b3, b4, b5, b6, b7};
  int m = blockIdx.x >> 4, tile = blockIdx.x & 15;
  int tr = (tile >> 2) * 32, tc = (tile & 3) * 32;
  int tx = t & 31, ty = t >> 5;   // 32 x 16
  const float* Wm = Ws[m];
  #pragma unroll
  for (int r = 0; r < 32; r += 16) tl[ty + r][tx] = Wm[(tr + ty + r) * 128 + tc + tx];
  __syncthreads();
  #pragma unroll
  for (int r = 0; r < 32; r += 16)
    Wcat[m * 16384 + (tc + ty + r) * 128 + tr + tx] = f2bf(tl[tx][ty + r]);
  if (tile == 0 && t < 128) Bcat[m * 128 + t] = bs[m][t];
}

// ---------------- CSR scan ----------------
__global__ void k_scan_a(const int* __restrict__ deg, int* __restrict__ rowptr,
                         int* __restrict__ bsum, int n) {
  __shared__ int tmp[512];
  int t = threadIdx.x, i = blockIdx.x * 512 + t;
  int v = (i < n) ? deg[i] : 0;
  tmp[t] = v;
  __syncthreads();
  for (int off = 1; off < 512; off <<= 1) {
    int u = (t >= off) ? tmp[t - off] : 0;
    __syncthreads();
    tmp[t] += u;
    __syncthreads();
  }
  if (i < n) rowptr[i] = tmp[t] - v;
  if (t == 511) bsum[blockIdx.x] = tmp[t];
}

__global__ void k_scan_c(int* __restrict__ rowptr, const int* __restrict__ bsum,
                         int n, int e, int nb) {
  __shared__ int sred[8];
  __shared__ int base_sh;
  int t = threadIdx.x;
  int v = (t < nb && t < (int)blockIdx.x) ? bsum[t] : 0;
  #pragma unroll
  for (int off = 32; off >= 1; off >>= 1) v += __shfl_xor(v, off);
  if ((t & 63) == 0) sred[t >> 6] = v;
  __syncthreads();
  if (t == 0) {
    int b = 0;
    #pragma unroll
    for (int j = 0; j < 8; ++j) b += sred[j];
    base_sh = b;
  }
  __syncthreads();
  int i = blockIdx.x * 512 + t;
  if (i < n) rowptr[i] += base_sh;
  if (i == 0) rowptr[n] = e;
}

// ---- atomic-free scatter: position = rowptr[dst] + rank (from hist pass) ----
__global__ __launch_bounds__(256) void k_scatter(
    const int* __restrict__ esrc, const int* __restrict__ edst,
    const int* __restrict__ rowptr, const int* __restrict__ rank,
    int* __restrict__ csrc, int e)
{
  for (int i = blockIdx.x * 256 + threadIdx.x; i < e; i += gridDim.x * 256)
    csrc[rowptr[edst[i]] + rank[i]] = esrc[i] << 9;   // byte offset into KVb
}

// ---------------- QKVS projection GEMM, split: y=0 -> Q,S ; y=1 -> K,V --------
// outputs: Q (f16, pre-scaled), KV quad-interleaved (f16): [k4p | v4p] per 16B, S (f16)
template<int ABF16>
__global__ __launch_bounds__(256, 3) void k_qkvs(
    const void* __restrict__ Ain, const unsigned short* __restrict__ Wl,
    const float* __restrict__ Bl, unsigned short* __restrict__ Qb,
    unsigned short* __restrict__ KVb, unsigned short* __restrict__ Sb, int n)
{
  __shared__ unsigned short sA[64 * 128];    // 16 KB
  __shared__ unsigned short sW[128 * 128];   // 32 KB
  const int tid = threadIdx.x;
  const int rb = blockIdx.x * 64;
  const int y = blockIdx.y;                  // 0: Q,S   1: K,V
  const float QSC = 0.25503487f;             // (1/sqrt(32)) * log2(e)

  if (ABF16) {
    const unsigned short* A = (const unsigned short*)Ain;
    #pragma unroll
    for (int it = 0; it < 4; ++it) {
      int q = tid + it * 256;
      int row = q >> 4, ch = q & 15;
      int gr = rb + row;
      short8 h = {0,0,0,0,0,0,0,0};
      if (gr < n) h = *reinterpret_cast<const short8*>(A + (size_t)gr * HID + ch * 8);
      *reinterpret_cast<short8*>(&sA[row * 128 + ((ch ^ (row & 7)) << 3)]) = h;
    }
  } else {
    const float* A = (const float*)Ain;
    #pragma unroll
    for (int it = 0; it < 8; ++it) {
      int q = tid + it * 256;
      int row = q >> 5, c4 = (q & 31) * 4;
      int gr = rb + row;
      f32x4 a = {0.f, 0.f, 0.f, 0.f};
      if (gr < n) a = *reinterpret_cast<const f32x4*>(A + (size_t)gr * HID + c4);
      short4v h;
      h.x = (short)f2bf(a.x); h.y = (short)f2bf(a.y);
      h.z = (short)f2bf(a.z); h.w = (short)f2bf(a.w);
      int eloff = row * 128 + (((c4 >> 3) ^ (row & 7)) << 3) + (c4 & 7);
      *reinterpret_cast<short4v*>(&sA[eloff]) = h;
    }
  }

  const int lane = tid & 63;
  const int wv = tid >> 6;

  auto stageW = [&](int w) {
    const unsigned short* Wy = Wl + (size_t)w * 16384;
    #pragma unroll
    for (int it = 0; it < 8; ++it) {
      int q = tid + it * 256;
      int c = q >> 4, ch = q & 15;
      short8 ww = *reinterpret_cast<const short8*>(Wy + c * 128 + ch * 8);
      *reinterpret_cast<short8*>(&sW[c * 128 + ((ch ^ (c & 7)) << 3)]) = ww;
    }
  };

  stageW(y == 0 ? 0 : 1);   // Wq or Wk
  __syncthreads();

  short8 af[4];
  #pragma unroll
  for (int ks = 0; ks < 4; ++ks) {
    int ch = ks * 4 + (lane >> 4);
    int row = wv * 16 + (lane & 15);
    af[ks] = *reinterpret_cast<const short8*>(&sA[row * 128 + ((ch ^ (row & 7)) << 3)]);
  }

  f32x4 acc[8];
  auto compute = [&]() {
    #pragma unroll
    for (int mf = 0; mf < 8; ++mf) acc[mf] = (f32x4){0.f, 0.f, 0.f, 0.f};
    #pragma unroll
    for (int ks = 0; ks < 4; ++ks) {
      int ch = ks * 4 + (lane >> 4);
      short8 wf[8];
      #pragma unroll
      for (int mf = 0; mf < 8; ++mf) {
        int wc = mf * 16 + (lane & 15);
        wf[mf] = *reinterpret_cast<const short8*>(&sW[wc * 128 + ((ch ^ (wc & 7)) << 3)]);
      }
      #pragma unroll
      for (int mf = 0; mf < 8; ++mf)
        acc[mf] = __builtin_amdgcn_mfma_f32_16x16x32_bf16(wf[mf], af[ks], acc[mf], 0, 0, 0);
    }
  };

  const int gr = rb + wv * 16 + (lane & 15);
  const int cbase = (lane >> 4) << 2;

  // ---- phase A: Q (y=0) or K (y=1, held in regs) ----
  compute();
  f32x4 kacc[8];
  if (y == 0) {
    if (gr < n) {
      #pragma unroll
      for (int mf = 0; mf < 8; ++mf) {
        int c0 = mf * 16 + cbase;
        f32x4 b = *reinterpret_cast<const f32x4*>(Bl + 0 * 128 + c0);
        f32x4 v = acc[mf];
        ushort4v h;
        h.x = f2h((v.x + b.x) * QSC); h.y = f2h((v.y + b.y) * QSC);
        h.z = f2h((v.z + b.z) * QSC); h.w = f2h((v.w + b.w) * QSC);
        *reinterpret_cast<ushort4v*>(Qb + (size_t)gr * HID + c0) = h;
      }
    }
  } else {
    #pragma unroll
    for (int mf = 0; mf < 8; ++mf) kacc[mf] = acc[mf];
  }

  // ---- phase B: S (y=0) or V+KV store (y=1) ----
  __syncthreads();
  stageW(y == 0 ? 3 : 2);   // Ws or Wv
  __syncthreads();
  compute();
  if (gr < n) {
    if (y == 0) {
      #pragma unroll
      for (int mf = 0; mf < 8; ++mf) {
        int c0 = mf * 16 + cbase;
        f32x4 b = *reinterpret_cast<const f32x4*>(Bl + 3 * 128 + c0);
        f32x4 v = acc[mf];
        ushort4v h;
        h.x = f2h(v.x + b.x); h.y = f2h(v.y + b.y);
        h.z = f2h(v.z + b.z); h.w = f2h(v.w + b.w);
        *reinterpret_cast<ushort4v*>(Sb + (size_t)gr * HID + c0) = h;
      }
    } else {
      #pragma unroll
      for (int mf = 0; mf < 8; ++mf) {
        int c0 = mf * 16 + cbase;
        f32x4 bk = *reinterpret_cast<const f32x4*>(Bl + 1 * 128 + c0);
        f32x4 bv = *reinterpret_cast<const f32x4*>(Bl + 2 * 128 + c0);
        f32x4 kv = kacc[mf], vv = acc[mf];
        short8 h;
        h[0] = (short)f2h(kv.x + bk.x); h[1] = (short)f2h(kv.y + bk.y);
        h[2] = (short)f2h(kv.z + bk.z); h[3] = (short)f2h(kv.w + bk.w);
        h[4] = (short)f2h(vv.x + bv.x); h[5] = (short)f2h(vv.y + bv.y);
        h[6] = (short)f2h(vv.z + bv.z); h[7] = (short)f2h(vv.w + bv.w);
        *reinterpret_cast<short8*>(KVb + (size_t)gr * 256 + 2 * c0) = h;
      }
    }
  }
}

// ---------------- fused attention + skip + relu ----------------
// 4-way edge parallelism: quarter q4 = lane>>4 processes edge 4b+q4.
// Lane owns 8 features (8*l16..8*l16+7) -> two contiguous 16B loads/edge.
// Head = 32 features = 4 lanes -> 2-op DPP reduce. 4 softmax states merged at end.
__global__ __launch_bounds__(256, 6) void k_attn2(
    const unsigned short* __restrict__ Qb, const unsigned short* __restrict__ KVb,
    const unsigned short* __restrict__ Sb, const int* __restrict__ rowptr,
    const int* __restrict__ csrc, unsigned short* __restrict__ Hout, int n)
{
  int wid = blockIdx.x * 4 + (threadIdx.x >> 6);
  if (wid >= n) return;
  const int lane = threadIdx.x & 63;
  const int l16 = lane & 15;        // feature-octet index
  const int q4 = lane >> 4;         // edge slot within batch

  // q features 8*l16 .. 8*l16+7 (pre-scaled by log2e/sqrt(32))
  uint4v qu = *reinterpret_cast<const uint4v*>(Qb + (size_t)wid * HID + 8 * l16);
  half2v qh0 = b2h2(qu.x), qh1 = b2h2(qu.y), qh2 = b2h2(qu.z), qh3 = b2h2(qu.w);

  int e0 = rowptr[wid], deg = rowptr[wid + 1] - e0;
  const int* cp = csrc + e0;
  const char* kvb = (const char*)KVb + l16 * 32;   // chunks 2*l16, 2*l16+1

  float m = -INFINITY, s = 0.f;
  float a0 = 0.f, a1 = 0.f, a2 = 0.f, a3 = 0.f;
  float a4 = 0.f, a5 = 0.f, a6 = 0.f, a7 = 0.f;

  auto LD0 = [&](int off) -> uint4v {
    return *reinterpret_cast<const uint4v*>(kvb + (unsigned)off);
  };
  auto LD1 = [&](int off) -> uint4v {
    return *reinterpret_cast<const uint4v*>(kvb + (unsigned)off + 16);
  };
  auto logit = [&](uint4v ka, uint4v kb) -> float {
    float d = __builtin_amdgcn_fdot2(qh1, b2h2(ka.y),
              __builtin_amdgcn_fdot2(qh0, b2h2(ka.x), 0.f, false), false);
    d = __builtin_amdgcn_fdot2(qh3, b2h2(kb.y),
        __builtin_amdgcn_fdot2(qh2, b2h2(kb.x), d, false), false);
    return dpp_rsum4(d);
  };
  auto accum = [&](float p, uint4v ka, uint4v kb) {
    half2v v0 = b2h2(ka.z), v1 = b2h2(ka.w);
    half2v v2 = b2h2(kb.z), v3 = b2h2(kb.w);
    a0 = fmaf(p, (float)v0.x, a0); a1 = fmaf(p, (float)v0.y, a1);
    a2 = fmaf(p, (float)v1.x, a2); a3 = fmaf(p, (float)v1.y, a3);
    a4 = fmaf(p, (float)v2.x, a4); a5 = fmaf(p, (float)v2.y, a5);
    a6 = fmaf(p, (float)v3.x, a6); a7 = fmaf(p, (float)v3.y, a7);
  };
  auto rescale = [&](float lg) {
    if (!__all(lg <= m + 11.5f)) {       // rare, wave-uniform
      float nm = fmaxf(m, lg);
      float cc = __builtin_amdgcn_exp2f(m - nm);
      s *= cc;
      a0 *= cc; a1 *= cc; a2 *= cc; a3 *= cc;
      a4 *= cc; a5 *= cc; a6 *= cc; a7 *= cc;
      m = nm;
    }
  };
  // one batch = 4 edges, one per quarter
  auto procB = [&](uint4v ka, uint4v kb) {
    float lg = logit(ka, kb);
    rescale(lg);
    float p = __builtin_amdgcn_exp2f(lg - m);
    s += p;
    accum(p, ka, kb);
  };
  auto proc1 = [&](int idx0) {         // masked tail batch
    int idx = idx0 + q4;
    bool valid = idx < deg;
    int off = valid ? cp[idx] : 0;
    uint4v ka = LD0(off), kb = LD1(off);
    float lg = logit(ka, kb);
    lg = valid ? lg : -INFINITY;
    rescale(lg);
    float p = valid ? __builtin_amdgcn_exp2f(lg - m) : 0.f;
    s += p;
    accum(p, ka, kb);
  };

  int nb = deg >> 2;           // full 4-edge batches
  if (nb >= 2) {
    int oA = cp[0 + q4], oB = cp[4 + q4];
    uint4v A0 = LD0(oA), A1 = LD1(oA);
    uint4v B0 = LD0(oB), B1 = LD1(oB);
    for (int b = 2; b < nb; ++b) {
      int oN = cp[4 * b + q4];
      uint4v N0 = LD0(oN), N1 = LD1(oN);
      procB(A0, A1);
      A0 = B0; A1 = B1;
      B0 = N0; B1 = N1;
    }
    procB(A0, A1);
    procB(B0, B1);
  } else if (nb == 1) {
    int o = cp[q4];
    procB(LD0(o), LD1(o));
  }
  if (deg & 3) proc1(nb * 4);

  // merge the 4 quarter softmax states: xor16 then xor32, guarded for -inf
  #pragma unroll
  for (int lvl = 16; lvl <= 32; lvl <<= 1) {
    float mo = __shfl_xor(m, lvl);
    float so = __shfl_xor(s, lvl);
    float b0 = __shfl_xor(a0, lvl), b1 = __shfl_xor(a1, lvl);
    float b2 = __shfl_xor(a2, lvl), b3 = __shfl_xor(a3, lvl);
    float b4 = __shfl_xor(a4, lvl), b5 = __shfl_xor(a5, lvl);
    float b6 = __shfl_xor(a6, lvl), b7 = __shfl_xor(a7, lvl);
    float M = fmaxf(m, mo);
    float c0 = (m  > -INFINITY) ? __builtin_amdgcn_exp2f(m  - M) : 0.f;
    float c1 = (mo > -INFINITY) ? __builtin_amdgcn_exp2f(mo - M) : 0.f;
    s = s * c0 + so * c1;
    a0 = a0 * c0 + b0 * c1; a1 = a1 * c0 + b1 * c1;
    a2 = a2 * c0 + b2 * c1; a3 = a3 * c0 + b3 * c1;
    a4 = a4 * c0 + b4 * c1; a5 = a5 * c0 + b5 * c1;
    a6 = a6 * c0 + b6 * c1; a7 = a7 * c0 + b7 * c1;
    m = M;
  }
  float inv = (s > 0.f) ? 1.f / s : 0.f;

  if (q4 == 0) {
    uint4v su = *reinterpret_cast<const uint4v*>(Sb + (size_t)wid * HID + 8 * l16);
    half2v s0 = b2h2(su.x), s1 = b2h2(su.y), s2 = b2h2(su.z), s3 = b2h2(su.w);
    short8 h;
    h[0] = (short)f2bf(fmaxf(fmaf(a0, inv, (float)s0.x), 0.f));
    h[1] = (short)f2bf(fmaxf(fmaf(a1, inv, (float)s0.y), 0.f));
    h[2] = (short)f2bf(fmaxf(fmaf(a2, inv, (float)s1.x), 0.f));
    h[3] = (short)f2bf(fmaxf(fmaf(a3, inv, (float)s1.y), 0.f));
    h[4] = (short)f2bf(fmaxf(fmaf(a4, inv, (float)s2.x), 0.f));
    h[5] = (short)f2bf(fmaxf(fmaf(a5, inv, (float)s2.y), 0.f));
    h[6] = (short)f2bf(fmaxf(fmaf(a6, inv, (float)s3.x), 0.f));
    h[7] = (short)f2bf(fmaxf(fmaf(a7, inv, (float)s3.y), 0.f));
    *reinterpret_cast<short8*>(Hout + (size_t)wid * HID + 8 * l16) = h;
  }
}

// ---------------- fused mean-pool + FC (64 blocks, one per group; zero atomics) --------
__global__ __launch_bounds__(256) void k_poolfc(
    const unsigned short* __restrict__ H, const int* __restrict__ batch,
    const float* __restrict__ Wfc, const float* __restrict__ bfc,
    float* __restrict__ out, int n)
{
  int g = blockIdx.x;
  int lo = 0, hi = n;
  while (lo < hi) { int mid = (lo + hi) >> 1; if (batch[mid] < g) lo = mid + 1; else hi = mid; }
  int start = lo;
  hi = n;
  while (lo < hi) { int mid = (lo + hi) >> 1; if (batch[mid] < g + 1) lo = mid + 1; else hi = mid; }
  int end = lo;

  int t = threadIdx.x;
  int col = t & 127, rr = t >> 7;        // 2 row-streams x 128 cols
  float a0 = 0.f, a1 = 0.f, a2 = 0.f, a3 = 0.f;
  int i = start + rr;
  for (; i + 6 < end; i += 8) {
    a0 += bf2f(H[(size_t)i * HID + col]);
    a1 += bf2f(H[(size_t)(i + 2) * HID + col]);
    a2 += bf2f(H[(size_t)(i + 4) * HID + col]);
    a3 += bf2f(H[(size_t)(i + 6) * HID + col]);
  }
  for (; i < end; i += 2) a0 += bf2f(H[(size_t)i * HID + col]);
  float v = ((a0 + a1) + (a2 + a3)) * Wfc[col];

  __shared__ float red[4];
  #pragma unroll
  for (int off = 32; off >= 1; off >>= 1) v += __shfl_xor(v, off);
  if ((t & 63) == 0) red[t >> 6] = v;
  __syncthreads();
  if (t == 0) {
    float tot = (red[0] + red[1]) + (red[2] + red[3]);
    float cnt = (float)(end - start);
    out[g] = tot / fmaxf(cnt, 1.f) + bfc[0];
  }
}

extern "C" void kernel_launch(void* const* d_in, const int* in_sizes, int n_in,
                              void* d_out, int out_size, void* d_ws, size_t ws_size,
                              hipStream_t stream)
{
  const float* x   = (const float*)d_in[0];
  const int*   ei  = (const int*)d_in[1];
  const int*   bat = (const int*)d_in[2];
  const float *Wq1 = (const float*)d_in[3],  *bq1 = (const float*)d_in[4];
  const float *Wk1 = (const float*)d_in[5],  *bk1 = (const float*)d_in[6];
  const float *Wv1 = (const float*)d_in[7],  *bv1 = (const float*)d_in[8];
  const float *Ws1 = (const float*)d_in[9],  *bs1 = (const float*)d_in[10];
  const float *Wq2 = (const float*)d_in[11], *bq2 = (const float*)d_in[12];
  const float *Wk2 = (const float*)d_in[13], *bk2 = (const float*)d_in[14];
  const float *Wv2 = (const float*)d_in[15], *bv2 = (const float*)d_in[16];
  const float *Ws2 = (const float*)d_in[17], *bs2 = (const float*)d_in[18];
  const float *Wfc = (const float*)d_in[19], *bfc = (const float*)d_in[20];
  float* out = (float*)d_out;

  const int N = in_sizes[0] / HID;
  const int E = in_sizes[1] / 2;
  const int G = 64;

  char* p = (char*)d_ws;
  auto alloc = [&](size_t bytes) -> char* { char* r = p; p += align256(bytes); return r; };
  unsigned short* Qb  = (unsigned short*)alloc((size_t)N * HID * 2);   // f16
  unsigned short* KVb = (unsigned short*)alloc((size_t)N * 256 * 2);   // f16 quad-interleaved
  unsigned short* Sb  = (unsigned short*)alloc((size_t)N * HID * 2);   // f16
  unsigned short* Hb  = (unsigned short*)alloc((size_t)N * HID * 2);   // bf16
  unsigned short* H2b = (unsigned short*)alloc((size_t)N * HID * 2);   // bf16
  unsigned short* Wcat = (unsigned short*)alloc((size_t)8 * 128 * 128 * 2);
  float* Bcat = (float*)alloc((size_t)8 * 128 * 4);
  int* rowptr = (int*)alloc((size_t)(N + 1) * sizeof(int));
  int* deg    = (int*)alloc((size_t)N * sizeof(int));
  int* rank   = (int*)alloc((size_t)E * sizeof(int));
  int* bsum   = (int*)alloc(4096);
  int* csrc   = (int*)alloc((size_t)E * sizeof(int));

  const int* esrc = ei;
  const int* edst = ei + E;

  hipMemsetAsync(deg, 0, (size_t)N * sizeof(int), stream);

  // wprep (blocks 0-127) || hist+rank (blocks 128-639)
  k_prep<<<640, 512, 0, stream>>>(
      Wq1, Wk1, Wv1, Ws1, Wq2, Wk2, Wv2, Ws2,
      bq1, bk1, bv1, bs1, bq2, bk2, bv2, bs2,
      Wcat, Bcat, edst, deg, rank, E);

  int SB = (N + 511) / 512;
  k_scan_a<<<SB, 512, 0, stream>>>(deg, rowptr, bsum, N);
  k_scan_c<<<SB, 512, 0, stream>>>(rowptr, bsum, N, E, SB);
  k_scatter<<<512, 256, 0, stream>>>(esrc, edst, rowptr, rank, csrc, E);

  int QB = (N + 63) / 64;
  dim3 qgrid(QB, 2);
  // layer 1 (fp32 input)
  k_qkvs<0><<<qgrid, 256, 0, stream>>>(x, Wcat, Bcat, Qb, KVb, Sb, N);
  k_attn2<<<(N + 3) / 4, 256, 0, stream>>>(Qb, KVb, Sb, rowptr, csrc, Hb, N);
  // layer 2 (bf16 input)
  k_qkvs<1><<<qgrid, 256, 0, stream>>>(Hb, Wcat + 4 * 16384, Bcat + 512, Qb, KVb, Sb, N);
  k_attn2<<<(N + 3) / 4, 256, 0, stream>>>(Qb, KVb, Sb, rowptr, csrc, H2b, N);
  // mean-pool + fc
  k_poolfc<<<G, 256, 0, stream>>>(H2b, bat, Wfc, bfc, out, N);
}